// Round 1
// baseline (255.479 us; speedup 1.0000x reference)
//
#include <hip/hip_runtime.h>

#define BLOCK 256

// ---------------------------------------------------------------------------
// Block-wide sum reduction: wave64 shuffle reduce, then LDS across waves.
// Safe to call multiple times per kernel (entry barrier).
// ---------------------------------------------------------------------------
__device__ __forceinline__ float block_reduce_sum(float v) {
    __shared__ float sm[BLOCK / 64];
    __syncthreads();
#pragma unroll
    for (int off = 32; off > 0; off >>= 1) v += __shfl_down(v, off, 64);
    const int lane = threadIdx.x & 63;
    const int wv = threadIdx.x >> 6;
    if (lane == 0) sm[wv] = v;
    __syncthreads();
    float s = sm[0];
#pragma unroll
    for (int i = 1; i < BLOCK / 64; ++i) s += sm[i];
    return s;
}

// ---------------------------------------------------------------------------
// Pass 1: partial sums of (p-t)^2, one float per block.
// ---------------------------------------------------------------------------
__global__ void pass1_mse_sum(const float4* __restrict__ p,
                              const float4* __restrict__ t,
                              float* __restrict__ partials,
                              int n4, int ntail, const float* __restrict__ ptail_p,
                              const float* __restrict__ ptail_t) {
    float acc = 0.0f;
    const int stride = gridDim.x * blockDim.x;
    for (int i = blockIdx.x * blockDim.x + threadIdx.x; i < n4; i += stride) {
        float4 a = p[i], b = t[i];
        float dx = a.x - b.x, dy = a.y - b.y, dz = a.z - b.z, dw = a.w - b.w;
        acc += dx * dx + dy * dy + dz * dz + dw * dw;
    }
    // scalar tail (N % 4), handled by one thread (N is 25165824 -> ntail==0)
    if (blockIdx.x == 0 && threadIdx.x == 0) {
        for (int i = 0; i < ntail; ++i) {
            float d = ptail_p[i] - ptail_t[i];
            acc += d * d;
        }
    }
    float s = block_reduce_sum(acc);
    if (threadIdx.x == 0) partials[blockIdx.x] = s;
}

// ---------------------------------------------------------------------------
// Mid: reduce partials -> K = mean(mse)+1e-8 ; reduce domain weights -> mean.
// domain_ids: harness doc says integers arrive as int32, but reference dtype
// is int64. Sniff the layout: if every odd 32-bit word of the first 128 words
// is zero, it is int64 (values are 0..2, so high words are 0). Probability of
// a false int64 verdict with true int32 data is (1/3)^64 ~ 0.
// ---------------------------------------------------------------------------
__global__ void mid_reduce(const float* __restrict__ partials, int nb,
                           const int* __restrict__ dom32,
                           const long long* __restrict__ dom64,
                           int B, float inv_n,
                           float* __restrict__ scalars) {
    __shared__ int is32;
    if (threadIdx.x == 0) is32 = 0;
    __syncthreads();

    float acc = 0.0f;
    for (int i = threadIdx.x; i < nb; i += blockDim.x) acc += partials[i];
    float tot = block_reduce_sum(acc);

    if (threadIdx.x < (unsigned)B) {
        int v = dom32[threadIdx.x];
        if ((threadIdx.x & 1) && v != 0) atomicOr(&is32, 1);
    }
    __syncthreads();

    float w = 0.0f;
    for (int i = threadIdx.x; i < B; i += blockDim.x) {
        int d = is32 ? dom32[i] : (int)dom64[i];
        w += (d == 0) ? 0.6502451783856802f
                      : ((d == 1) ? 1.449137674618944f : 2.509980079602226f);
    }
    float wt = block_reduce_sum(w);

    if (threadIdx.x == 0) {
        scalars[0] = tot * inv_n + 1e-8f;   // K = mean + eps
        scalars[1] = wt / (float)B;         // mean domain weight
    }
}

// ---------------------------------------------------------------------------
// Pass 2: partial sums of (m/(m+K))^2 * m.
// ---------------------------------------------------------------------------
__global__ void pass2_focal_sum(const float4* __restrict__ p,
                                const float4* __restrict__ t,
                                const float* __restrict__ scalars,
                                float* __restrict__ partials,
                                int n4, int ntail, const float* __restrict__ ptail_p,
                                const float* __restrict__ ptail_t) {
    const float K = scalars[0];
    float acc = 0.0f;
    const int stride = gridDim.x * blockDim.x;
    for (int i = blockIdx.x * blockDim.x + threadIdx.x; i < n4; i += stride) {
        float4 a = p[i], b = t[i];
        float d0 = a.x - b.x, d1 = a.y - b.y, d2 = a.z - b.z, d3 = a.w - b.w;
        float m0 = d0 * d0, m1 = d1 * d1, m2 = d2 * d2, m3 = d3 * d3;
        float r0 = m0 / (m0 + K), r1 = m1 / (m1 + K);
        float r2 = m2 / (m2 + K), r3 = m3 / (m3 + K);
        acc += r0 * r0 * m0 + r1 * r1 * m1 + r2 * r2 * m2 + r3 * r3 * m3;
    }
    if (blockIdx.x == 0 && threadIdx.x == 0) {
        for (int i = 0; i < ntail; ++i) {
            float d = ptail_p[i] - ptail_t[i];
            float m = d * d;
            float r = m / (m + K);
            acc += r * r * m;
        }
    }
    float s = block_reduce_sum(acc);
    if (threadIdx.x == 0) partials[blockIdx.x] = s;
}

// ---------------------------------------------------------------------------
// Final: reduce pass-2 partials -> scalar output.
// ---------------------------------------------------------------------------
__global__ void final_reduce(const float* __restrict__ partials, int nb,
                             const float* __restrict__ scalars,
                             float inv_n, float* __restrict__ out) {
    float acc = 0.0f;
    for (int i = threadIdx.x; i < nb; i += blockDim.x) acc += partials[i];
    float tot = block_reduce_sum(acc);
    if (threadIdx.x == 0) {
        float focal = 0.25f * tot * inv_n;
        out[0] = focal * scalars[1];
    }
}

extern "C" void kernel_launch(void* const* d_in, const int* in_sizes, int n_in,
                              void* d_out, int out_size, void* d_ws, size_t ws_size,
                              hipStream_t stream) {
    const float* pred = (const float*)d_in[0];
    const float* targ = (const float*)d_in[1];
    const int* dom32 = (const int*)d_in[2];
    const long long* dom64 = (const long long*)d_in[2];

    const int N = in_sizes[0];
    const int n4 = N >> 2;
    const int ntail = N & 3;
    const int B = in_sizes[2];
    const float inv_n = 1.0f / (float)N;

    // Workspace layout: [part1: grid][part2: grid][scalars: 2]
    int grid = 2048;  // 8 blocks/CU, plenty of waves to hide HBM latency
    size_t avail = ws_size / sizeof(float);
    while ((size_t)(2 * grid + 2) > avail && grid > 1) grid >>= 1;

    float* ws = (float*)d_ws;
    float* part1 = ws;
    float* part2 = ws + grid;
    float* scal = ws + 2 * grid;

    const float* tail_p = pred + (size_t)n4 * 4;
    const float* tail_t = targ + (size_t)n4 * 4;

    pass1_mse_sum<<<grid, BLOCK, 0, stream>>>(
        (const float4*)pred, (const float4*)targ, part1, n4, ntail, tail_p, tail_t);
    mid_reduce<<<1, BLOCK, 0, stream>>>(part1, grid, dom32, dom64, B, inv_n, scal);
    pass2_focal_sum<<<grid, BLOCK, 0, stream>>>(
        (const float4*)pred, (const float4*)targ, scal, part2, n4, ntail, tail_p, tail_t);
    final_reduce<<<1, BLOCK, 0, stream>>>(part2, grid, scal, inv_n, (float*)d_out);
}